// Round 9
// baseline (1399.152 us; speedup 1.0000x reference)
//
#include <hip/hip_runtime.h>
#include <hip/hip_bf16.h>
#include <math.h>

// Problem constants
#define BB 2
#define CC 1024
#define HH 64
#define WW 64
#define HWH (HH*WW)          // 4096
#define TT (BB*HWH)          // 8192 tokens
#define EE 8
#define FFN 1024
// 256-row m-tiles: sum_e ceil(cnt_e/256) <= 16384/256 + (E-1) = 71
#define MAXTILES 71
#define HCAP (MAXTILES*256)  // 18176 padded rows

typedef __bf16 bf16x8 __attribute__((ext_vector_type(8)));
typedef float  f32x4  __attribute__((ext_vector_type(4)));

// async global->LDS, 16B per lane. LDS dest = wave-uniform base + lane*16.
__device__ __forceinline__ void gl_lds16(const __bf16* g, __bf16* l) {
    __builtin_amdgcn_global_load_lds(
        (const __attribute__((address_space(1))) void*)g,
        (__attribute__((address_space(3))) void*)l, 16, 0, 0);
}

__device__ __forceinline__ void barrier_raw() {
    asm volatile("" ::: "memory");
    __builtin_amdgcn_s_barrier();
    asm volatile("" ::: "memory");
}

// bijective XCD chunk swizzle (m204): consecutive work-ids -> same XCD chunk.
__device__ __forceinline__ int xcd_swz(int orig, int nwg) {
    const int q = nwg >> 3, r = nwg & 7, x = orig & 7, o8 = orig >> 3;
    return (x < r ? x * (q + 1) : r * (q + 1) + (x - r) * q) + o8;
}

// fast exact-enough GELU (tanh form): max |diff vs erf-GELU| ~7e-4, below
// bf16 ulp of H. exp2-based: gelu(a) = a / (1 + exp(-1.5957691*(a+0.044715a^3)))
__device__ __forceinline__ float gelu_fast(float a) {
    const float a2 = a * a;
    const float t  = a * fmaf(0.044715f, a2, 1.0f);
    const float u  = __builtin_amdgcn_exp2f(t * -2.30220795f);
    return a * __builtin_amdgcn_rcpf(1.0f + u);
}

#define WAITV(N) asm volatile("s_waitcnt vmcnt(" #N ")" ::: "memory")
#define PRIO1()  __builtin_amdgcn_s_setprio(1)
#define PRIO0()  __builtin_amdgcn_s_setprio(0)

// ---------------------------------------------------------------------------
// k_prep: one launch doing (a) w1/w2/w3 fp32->bf16, (b) hs transpose -> X bf16,
// (c) router partial logits (16-way K-split).  All memory-bound, overlapped.
// ---------------------------------------------------------------------------
#define CVB 12288
#define XPB 8192
#define RTB 512
__global__ __launch_bounds__(256) void k_prep(
    const float* __restrict__ hs, const float* __restrict__ gate_w,
    const float* __restrict__ w1, const float* __restrict__ w2,
    const float* __restrict__ w3,
    __bf16* __restrict__ w1b, __bf16* __restrict__ w2b,
    __bf16* __restrict__ w3b, __bf16* __restrict__ X,
    float* __restrict__ logP) {
    __shared__ float sm[2112];   // union: xpose tile 32x33 | router gate 8x256
    const int bid = blockIdx.x;
    const int tid = threadIdx.x;

    if (bid < CVB) {
        // --- weight convert: 8 elems/thread ---
        const float* s; __bf16* d; int lb = bid;
        if (lb < 4096)      { s = w1; d = w1b; }
        else if (lb < 8192) { s = w2; d = w2b; lb -= 4096; }
        else                { s = w3; d = w3b; lb -= 8192; }
        const size_t i = (size_t)lb * 2048 + (size_t)tid * 8;
        const f32x4 v0 = *(const f32x4*)&s[i];
        const f32x4 v1 = *(const f32x4*)&s[i + 4];
        bf16x8 o;
#pragma unroll
        for (int j = 0; j < 4; ++j) { o[j] = (__bf16)v0[j]; o[4 + j] = (__bf16)v1[j]; }
        *(bf16x8*)&d[i] = o;
    } else if (bid < CVB + XPB) {
        // --- transpose hs (B,C,H,W) -> X [T,C] bf16 ---
        const int lb  = bid - CVB;
        const int hw0 = (lb & 127) * 32;
        const int c0  = ((lb >> 7) & 31) * 32;
        const int b   = lb >> 12;
        float (*tile)[33] = (float(*)[33])sm;
        const int tx = tid & 31, ty = tid >> 5;
        const float* src = hs + ((size_t)b * CC + c0) * HWH + hw0;
#pragma unroll
        for (int i = 0; i < 4; ++i)
            tile[ty + i * 8][tx] = src[(size_t)(ty + i * 8) * HWH + tx];
        __syncthreads();
        __bf16* dst = X + ((size_t)b * HWH + hw0) * CC + c0;
#pragma unroll
        for (int i = 0; i < 4; ++i) {
            const int hwl = ty + i * 8;
            dst[(size_t)hwl * CC + tx] = (__bf16)tile[tx][hwl];
        }
    } else {
        // --- router partial: block = (tokblk, quarter q); thread = (q2, token) ---
        const int lb  = bid - (CVB + XPB);
        const int q   = lb & 3;
        const int t64 = lb >> 2;
        float* g = sm;   // [8][256] slice of gate for channels [q*256, +256)
        for (int i = tid; i < 2048; i += 256)
            g[i] = gate_w[(size_t)(i >> 8) * CC + q * 256 + (i & 255)];
        __syncthreads();
        const int q2 = tid >> 6, tl = tid & 63;
        const int t  = t64 * 64 + tl;
        const int b  = t >> 12, hw = t & 4095;
        const float* xp = hs + (size_t)b * CC * HWH + hw;
        float l[EE];
#pragma unroll
        for (int e = 0; e < EE; ++e) l[e] = 0.0f;
        const int cbase = q * 256 + q2 * 64;
        for (int c2 = 0; c2 < 64; ++c2) {
            const float xv = xp[(size_t)(cbase + c2) * HWH];
#pragma unroll
            for (int e = 0; e < EE; ++e) l[e] += xv * g[e * 256 + q2 * 64 + c2];
        }
        float* dst = logP + ((size_t)(q * 4 + q2) * TT + t) * 8;
        f32x4 a, c;
#pragma unroll
        for (int e = 0; e < 4; ++e) { a[e] = l[e]; c[e] = l[4 + e]; }
        *(f32x4*)dst = a;
        *(f32x4*)&dst[4] = c;
    }
}

// ---------------------------------------------------------------------------
// k_top2: reduce 16 partials, top-2, renormalize, block-aggregated atomics.
// ---------------------------------------------------------------------------
__global__ __launch_bounds__(256) void k_top2(const float* __restrict__ logP,
                                              int* __restrict__ cnt,
                                              int* __restrict__ idxl,
                                              int* __restrict__ tokE,
                                              int* __restrict__ tokP,
                                              float* __restrict__ tokW) {
    __shared__ int lcnt[EE], lbase[EE];
    const int tid = threadIdx.x;
    const int t   = blockIdx.x * 256 + tid;
    if (tid < EE) lcnt[tid] = 0;
    __syncthreads();

    float l[EE];
#pragma unroll
    for (int e = 0; e < EE; ++e) l[e] = 0.0f;
#pragma unroll
    for (int pq = 0; pq < 16; ++pq) {
        const float* src = logP + ((size_t)pq * TT + t) * 8;
        const f32x4 a = *(const f32x4*)src;
        const f32x4 c = *(const f32x4*)&src[4];
#pragma unroll
        for (int e = 0; e < 4; ++e) { l[e] += a[e]; l[4 + e] += c[e]; }
    }

    int e1 = 0; float v1 = l[0];
#pragma unroll
    for (int e = 1; e < EE; ++e) { if (l[e] > v1) { v1 = l[e]; e1 = e; } }
    int e2 = -1; float v2 = -1e30f;
#pragma unroll
    for (int e = 0; e < EE; ++e) { if (e != e1 && l[e] > v2) { v2 = l[e]; e2 = e; } }

    const float p2 = __expf(v2 - v1);
    const float rs = 1.0f / (1.0f + p2);

    const int m1 = atomicAdd(&lcnt[e1], 1);
    const int m2 = atomicAdd(&lcnt[e2], 1);
    __syncthreads();
    if (tid < EE) lbase[tid] = atomicAdd(&cnt[tid], lcnt[tid]);
    __syncthreads();
    const int p1pos = lbase[e1] + m1;
    const int p2pos = lbase[e2] + m2;

    idxl[e1 * TT + p1pos] = t;
    idxl[e2 * TT + p2pos] = t;
    tokE[t] = e1 | (e2 << 8);
    tokP[2 * t]     = p1pos;
    tokP[2 * t + 1] = p2pos;
    tokW[2 * t]     = rs;
    tokW[2 * t + 1] = p2 * rs;
}

// ---------------------------------------------------------------------------
// Shared GEMM tile body: 2-slot LDS ring, BK=32, 1 barrier/tile.
// Tile t: stage tile t+1 into slot (t+1)&1 (issued FIRST, flies under the
// whole tile body ~1800 cyc >> L2 latency), read slot t&1, MFMA, vmcnt(0)
// (pre-satisfied), barrier.  Slot overwrite is >=1 barrier after its last
// read (reads are consumed by MFMAs before the barrier) -> race-free.
// ---------------------------------------------------------------------------
#define GT_TILE(SR, SS, KB, STG) do {                                         \
    if (STG) {                                                                \
        gl_lds16(gA0 + (KB), &sA[SS][stA]);                                   \
        gl_lds16(gA1 + (KB), &sA[SS][stA + 4096]);                            \
        gl_lds16(gB0 + (KB), &sB[SS][stA]);                                   \
    }                                                                         \
    bf16x8 af[4], bv[4];                                                      \
    _Pragma("unroll") for (int f_ = 0; f_ < 4; ++f_) {                        \
        af[f_] = *(const bf16x8*)&sA[SR][aoff + f_ * 512];                    \
        bv[f_] = *(const bf16x8*)&sB[SR][boff + f_ * 512];                    \
    }                                                                         \
    PRIO1();                                                                  \
    _Pragma("unroll") for (int m_ = 0; m_ < 4; ++m_)                          \
    _Pragma("unroll") for (int n_ = 0; n_ < 4; ++n_)                          \
        acc[m_][n_] = __builtin_amdgcn_mfma_f32_16x16x32_bf16(                \
            af[m_], bv[n_], acc[m_][n_], 0, 0, 0);                            \
    PRIO0();                                                                  \
    if (STG) WAITV(0);                                                        \
    barrier_raw();                                                            \
} while (0)

// ---------------------------------------------------------------------------
// GEMM1: H = gelu(X@W1^T)*(X@W3^T), bf16, grouped.
// BM=256, BN=64 (dual weights: B-LDS = 64 W1-rows + 64 W3-rows), BK=32.
// 8 waves (4m x 2n), per-wave 64x64.  2-slot ring -> LDS 48 KiB ->
// __launch_bounds__(512,6) = 3 blocks/CU (768 resident blocks: gemm1 grid
// 1136 -> 2 rounds, was 3).  grid (FFN/64, MAXTILES), XCD-swizzled.
// ---------------------------------------------------------------------------
__global__ __launch_bounds__(512, 6)
void k_gemm1(const __bf16* __restrict__ X, const __bf16* __restrict__ w1b,
             const __bf16* __restrict__ w3b, const int* __restrict__ cnt,
             const int* __restrict__ idxl, __bf16* __restrict__ H) {
    const int lid = blockIdx.y * 16 + blockIdx.x;
    const int wg  = xcd_swz(lid, 16 * MAXTILES);
    const int n0  = (wg & 15) * 64;          // H-column base
    int ty = wg >> 4;
    int e = -1, mt = 0, goff = 0, acc_rows = 0;
#pragma unroll
    for (int ee = 0; ee < EE; ++ee) {
        const int me = (cnt[ee] + 255) >> 8;
        if (ty >= 0 && ty < me) { e = ee; mt = ty << 8; goff = acc_rows; }
        ty -= me;
        acc_rows += me << 8;
    }
    if (e < 0) return;
    const int cntE = cnt[e];
    const __bf16* W1 = w1b + (size_t)e * FFN * CC;
    const __bf16* W3 = w3b + (size_t)e * FFN * CC;

    __shared__ __align__(16) __bf16 sA[2][8192];   // 32 KiB: 256 rows x 32
    __shared__ __align__(16) __bf16 sB[2][4096];   // 16 KiB: 128 rows x 32

    const int tid  = threadIdx.x;
    const int lane = tid & 63, wave = tid >> 6;
    const int l15  = lane & 15, lq = lane >> 4;
    const int wm   = wave & 3;     // 4 m-quarters (64 rows each)
    const int wq   = wave >> 2;    // 2 n-halves (32 H-cols each)
    const int rsw  = (lq ^ ((l15 >> 1) & 3)) * 8;        // frag-read swizzle

    // staging swizzle (row parity built in; 16-row-aligned bases keep it exact)
    const int csw  = ((tid & 3) ^ ((tid >> 3) & 3)) * 8;    // A: row=tid>>2
    const int cswb = ((lane & 3) ^ ((lane >> 3) & 3)) * 8;  // B: row=w*16+(l>>2)

    // A: gathered token rows mt + {0,128} + tid>>2 (clamped)
    int pr0 = mt + (tid >> 2);        if (pr0 > cntE - 1) pr0 = cntE - 1;
    int pr1 = mt + 128 + (tid >> 2);  if (pr1 > cntE - 1) pr1 = cntE - 1;
    const __bf16* gA0 = X + (size_t)idxl[e * TT + pr0] * CC + csw;
    const __bf16* gA1 = X + (size_t)idxl[e * TT + pr1] * CC + csw;
    // B: wave w stages B-LDS rows [w*16, w*16+16) from (w odd ? W3 : W1),
    // cols n0 + (w>>1)*16 + (lane>>2)
    const __bf16* WB  = (wave & 1) ? W3 : W1;
    const __bf16* gB0 = WB + (size_t)(n0 + (wave >> 1) * 16 + (lane >> 2)) * CC + cswb;

    const int stA  = wave * 512;                  // stage LDS elem base
    const int aoff = (wm * 64 + l15) * 32 + rsw;  // + mf*512
    const int boff = (wq * 64 + l15) * 32 + rsw;  // + nf*512

    f32x4 acc[4][4] = {};

    // prologue: stage tile 0 -> slot 0
    gl_lds16(gA0, &sA[0][stA]); gl_lds16(gA1, &sA[0][stA + 4096]);
    gl_lds16(gB0, &sB[0][stA]);
    WAITV(0);
    barrier_raw();

    int kb = 32;
    for (int it = 0; it < 15; ++it) {
        GT_TILE(0, 1, kb, 1); kb += 32;
        GT_TILE(1, 0, kb, 1); kb += 32;
    }
    GT_TILE(0, 1, kb, 1);   // tile 30, stages tile 31 (kb=992)
    GT_TILE(1, 0, 0, 0);    // tile 31, no stage

    // epilogue: nf0=W1 / nf1=W3 @ col, nf2=W1 / nf3=W3 @ col+16
#pragma unroll
    for (int mf = 0; mf < 4; ++mf) {
        const int gr  = goff + mt + wm * 64 + mf * 16 + lq * 4;
        const int col = n0 + wq * 32 + l15;
#pragma unroll
        for (int r = 0; r < 4; ++r) {
            const float a0 = acc[mf][0][r], c0 = acc[mf][1][r];
            const float a1 = acc[mf][2][r], c1 = acc[mf][3][r];
            H[(size_t)(gr + r) * FFN + col]      = (__bf16)(gelu_fast(a0) * c0);
            H[(size_t)(gr + r) * FFN + col + 16] = (__bf16)(gelu_fast(a1) * c1);
        }
    }
}

// ---------------------------------------------------------------------------
// GEMM2: Z = H @ W2^T, bf16, grouped. BM=256, BN=128, BK=32, 2-slot ring,
// 3 blocks/CU (568 blocks -> ALL resident, single round; was 2 rounds).
// grid (CC/128, MAXTILES), XCD-swizzled.
// ---------------------------------------------------------------------------
__global__ __launch_bounds__(512, 6)
void k_gemm2(const __bf16* __restrict__ H, const __bf16* __restrict__ w2b,
             const int* __restrict__ cnt, __bf16* __restrict__ Z) {
    const int lid = blockIdx.y * 8 + blockIdx.x;
    const int wg  = xcd_swz(lid, 8 * MAXTILES);
    const int n0  = (wg & 7) * 128;
    int ty = wg >> 3;
    int e = -1, mt = 0, goff = 0, acc_rows = 0;
#pragma unroll
    for (int ee = 0; ee < EE; ++ee) {
        const int me = (cnt[ee] + 255) >> 8;
        if (ty >= 0 && ty < me) { e = ee; mt = ty << 8; goff = acc_rows; }
        ty -= me;
        acc_rows += me << 8;
    }
    if (e < 0) return;
    const __bf16* W2 = w2b + (size_t)e * CC * FFN;
    const __bf16* Ar = H + (size_t)(goff + mt) * FFN;

    __shared__ __align__(16) __bf16 sA[2][8192];   // 32 KiB
    __shared__ __align__(16) __bf16 sB[2][4096];   // 16 KiB

    const int tid  = threadIdx.x;
    const int lane = tid & 63, wave = tid >> 6;
    const int l15  = lane & 15, lq = lane >> 4;
    const int wm   = wave & 3;
    const int wq   = wave >> 2;
    const int rsw  = (lq ^ ((l15 >> 1) & 3)) * 8;
    const int csw  = ((tid & 3) ^ ((tid >> 3) & 3)) * 8;
    const int cswb = ((lane & 3) ^ ((lane >> 3) & 3)) * 8;

    const __bf16* gA0 = Ar + (size_t)(tid >> 2) * FFN + csw;
    const __bf16* gA1 = Ar + (size_t)(128 + (tid >> 2)) * FFN + csw;
    // B: wave w stages B-LDS rows [w*16, w*16+16) from W2 rows n0+w*16+(l>>2)
    const __bf16* gB0 = W2 + (size_t)(n0 + wave * 16 + (lane >> 2)) * FFN + cswb;

    const int stA  = wave * 512;
    const int aoff = (wm * 64 + l15) * 32 + rsw;
    const int boff = (wq * 64 + l15) * 32 + rsw;

    f32x4 acc[4][4] = {};

    gl_lds16(gA0, &sA[0][stA]); gl_lds16(gA1, &sA[0][stA + 4096]);
    gl_lds16(gB0, &sB[0][stA]);
    WAITV(0);
    barrier_raw();

    int kb = 32;
    for (int it = 0; it < 15; ++it) {
        GT_TILE(0, 1, kb, 1); kb += 32;
        GT_TILE(1, 0, kb, 1); kb += 32;
    }
    GT_TILE(0, 1, kb, 1);   // tile 30
    GT_TILE(1, 0, 0, 0);    // tile 31

#pragma unroll
    for (int mf = 0; mf < 4; ++mf) {
        const int gr = goff + mt + wm * 64 + mf * 16 + lq * 4;
#pragma unroll
        for (int nf = 0; nf < 4; ++nf) {
            const int col = n0 + wq * 64 + nf * 16 + l15;
#pragma unroll
            for (int r = 0; r < 4; ++r)
                Z[(size_t)(gr + r) * CC + col] = (__bf16)acc[mf][nf][r];
        }
    }
}

// ---------------------------------------------------------------------------
// k_combine: out[t,c] = w1*Z[r1,c] + w2*Z[r2,c], transposed to (B,C,H,W).
// Expert row offsets computed inline from cnt.
// ---------------------------------------------------------------------------
__global__ __launch_bounds__(256) void k_combine(const __bf16* __restrict__ Z,
                                                 const int* __restrict__ cnt,
                                                 const int* __restrict__ tokE,
                                                 const int* __restrict__ tokP,
                                                 const float* __restrict__ tokW,
                                                 float* __restrict__ out) {
    __shared__ float tile[32][33];
    __shared__ int s_pre[EE];
    const int tid = threadIdx.x;
    if (tid < EE) {
        int a = 0;
        for (int ee = 0; ee < tid; ++ee) a += ((cnt[ee] + 255) >> 8) << 8;
        s_pre[tid] = a;
    }
    __syncthreads();

    const int t0 = blockIdx.x * 32;
    const int c0 = blockIdx.y * 32;
    const int tx = tid & 31;
    const int ty = tid >> 5;

#pragma unroll
    for (int i = 0; i < 4; ++i) {
        const int tl = ty + 8 * i;
        const int t  = t0 + tl;
        const int ee = tokE[t];
        const int e1 = ee & 0xff, e2 = ee >> 8;
        const int r1 = s_pre[e1] + tokP[2 * t];
        const int r2 = s_pre[e2] + tokP[2 * t + 1];
        const float v = tokW[2 * t]     * (float)Z[(size_t)r1 * CC + c0 + tx]
                      + tokW[2 * t + 1] * (float)Z[(size_t)r2 * CC + c0 + tx];
        tile[tl][tx] = v;
    }
    __syncthreads();

    const int b   = t0 >> 12;
    const int hw0 = t0 & 4095;
#pragma unroll
    for (int i = 0; i < 4; ++i) {
        const int cl = ty + 8 * i;
        out[(size_t)b * CC * HWH + (size_t)(c0 + cl) * HWH + hw0 + tx] = tile[tx][cl];
    }
}

// ---------------------------------------------------------------------------
extern "C" void kernel_launch(void* const* d_in, const int* in_sizes, int n_in,
                              void* d_out, int out_size, void* d_ws, size_t ws_size,
                              hipStream_t stream) {
    const float* hs     = (const float*)d_in[0];
    const float* gate_w = (const float*)d_in[1];
    const float* w1     = (const float*)d_in[2];
    const float* w2     = (const float*)d_in[3];
    const float* w3     = (const float*)d_in[4];
    float* out = (float*)d_out;

    const size_t WSZ = (size_t)EE * FFN * CC * 2;   // 16 MB per bf16 weight
    char* ws = (char*)d_ws;
    __bf16* w2b  = (__bf16*)ws;                     // [0, 16M)   live: gemm2
    __bf16* w1b  = (__bf16*)(ws + WSZ);             // [16M,32M)  live: gemm1
    __bf16* w3b  = (__bf16*)(ws + 2 * WSZ);         // [32M,48M)  live: gemm1
    __bf16* X    = (__bf16*)(ws + 3 * WSZ);         // [48M,64M)  live: gemm1
    __bf16* Zbuf = (__bf16*)(ws + WSZ);             // overlays w1b,w3b,X-head
    __bf16* Hbuf = (__bf16*)(ws + 4 * WSZ);         // ~35.5 MiB
    float*  logP = (float*)Hbuf;                    // 4 MB, dead before gemm1
    char* p = ws + 4 * WSZ + (size_t)HCAP * FFN * 2;
    int*   idxl  = (int*)p;           p += (size_t)EE * TT * 4;
    int*   tokE  = (int*)p;           p += (size_t)TT * 4;
    int*   tokP  = (int*)p;           p += (size_t)2 * TT * 4;
    float* tokW  = (float*)p;         p += (size_t)2 * TT * 4;
    int*   cnt   = (int*)p;           p += 256;

    hipMemsetAsync(cnt, 0, EE * sizeof(int), stream);

    k_prep<<<CVB + XPB + RTB, 256, 0, stream>>>(
        hs, gate_w, w1, w2, w3, w1b, w2b, w3b, X, logP);
    k_top2<<<TT / 256, 256, 0, stream>>>(logP, cnt, idxl, tokE, tokP, tokW);

    k_gemm1<<<dim3(FFN / 64, MAXTILES), 512, 0, stream>>>(
        X, w1b, w3b, cnt, idxl, Hbuf);
    k_gemm2<<<dim3(CC / 128, MAXTILES), 512, 0, stream>>>(
        Hbuf, w2b, cnt, Zbuf);
    k_combine<<<dim3(TT / 32, CC / 32), 256, 0, stream>>>(
        Zbuf, cnt, tokE, tokP, tokW, out);
}

// Round 11
// 809.347 us; speedup vs baseline: 1.7287x; 1.7287x over previous
//
#include <hip/hip_runtime.h>
#include <hip/hip_bf16.h>
#include <math.h>

// Problem constants
#define BB 2
#define CC 1024
#define HH 64
#define WW 64
#define HWH (HH*WW)          // 4096
#define TT (BB*HWH)          // 8192 tokens
#define EE 8
#define FFN 1024
// 256-row m-tiles: sum_e ceil(cnt_e/256) <= 16384/256 + (E-1) = 71
#define MAXTILES 71
#define HCAP (MAXTILES*256)  // 18176 padded rows

typedef __bf16 bf16x8 __attribute__((ext_vector_type(8)));
typedef float  f32x4  __attribute__((ext_vector_type(4)));

// async global->LDS, 16B per lane. LDS dest = wave-uniform base + lane*16.
__device__ __forceinline__ void gl_lds16(const __bf16* g, __bf16* l) {
    __builtin_amdgcn_global_load_lds(
        (const __attribute__((address_space(1))) void*)g,
        (__attribute__((address_space(3))) void*)l, 16, 0, 0);
}

__device__ __forceinline__ void barrier_raw() {
    asm volatile("" ::: "memory");
    __builtin_amdgcn_s_barrier();
    asm volatile("" ::: "memory");
}

// bijective XCD chunk swizzle (m204): consecutive work-ids -> same XCD chunk.
__device__ __forceinline__ int xcd_swz(int orig, int nwg) {
    const int q = nwg >> 3, r = nwg & 7, x = orig & 7, o8 = orig >> 3;
    return (x < r ? x * (q + 1) : r * (q + 1) + (x - r) * q) + o8;
}

// fast exact-enough GELU (tanh form): max |diff vs erf-GELU| ~7e-4, below
// bf16 ulp of H.
__device__ __forceinline__ float gelu_fast(float a) {
    const float a2 = a * a;
    const float t  = a * fmaf(0.044715f, a2, 1.0f);
    const float u  = __builtin_amdgcn_exp2f(t * -2.30220795f);
    return a * __builtin_amdgcn_rcpf(1.0f + u);
}

#define WAITV(N) asm volatile("s_waitcnt vmcnt(" #N ")" ::: "memory")
#define PRIO1()  __builtin_amdgcn_s_setprio(1)
#define PRIO0()  __builtin_amdgcn_s_setprio(0)

// ---------------------------------------------------------------------------
// k_prep (unchanged R8)
// ---------------------------------------------------------------------------
#define CVB 12288
#define XPB 8192
#define RTB 512
__global__ __launch_bounds__(256) void k_prep(
    const float* __restrict__ hs, const float* __restrict__ gate_w,
    const float* __restrict__ w1, const float* __restrict__ w2,
    const float* __restrict__ w3,
    __bf16* __restrict__ w1b, __bf16* __restrict__ w2b,
    __bf16* __restrict__ w3b, __bf16* __restrict__ X,
    float* __restrict__ logP) {
    __shared__ float sm[2112];
    const int bid = blockIdx.x;
    const int tid = threadIdx.x;

    if (bid < CVB) {
        const float* s; __bf16* d; int lb = bid;
        if (lb < 4096)      { s = w1; d = w1b; }
        else if (lb < 8192) { s = w2; d = w2b; lb -= 4096; }
        else                { s = w3; d = w3b; lb -= 8192; }
        const size_t i = (size_t)lb * 2048 + (size_t)tid * 8;
        const f32x4 v0 = *(const f32x4*)&s[i];
        const f32x4 v1 = *(const f32x4*)&s[i + 4];
        bf16x8 o;
#pragma unroll
        for (int j = 0; j < 4; ++j) { o[j] = (__bf16)v0[j]; o[4 + j] = (__bf16)v1[j]; }
        *(bf16x8*)&d[i] = o;
    } else if (bid < CVB + XPB) {
        const int lb  = bid - CVB;
        const int hw0 = (lb & 127) * 32;
        const int c0  = ((lb >> 7) & 31) * 32;
        const int b   = lb >> 12;
        float (*tile)[33] = (float(*)[33])sm;
        const int tx = tid & 31, ty = tid >> 5;
        const float* src = hs + ((size_t)b * CC + c0) * HWH + hw0;
#pragma unroll
        for (int i = 0; i < 4; ++i)
            tile[ty + i * 8][tx] = src[(size_t)(ty + i * 8) * HWH + tx];
        __syncthreads();
        __bf16* dst = X + ((size_t)b * HWH + hw0) * CC + c0;
#pragma unroll
        for (int i = 0; i < 4; ++i) {
            const int hwl = ty + i * 8;
            dst[(size_t)hwl * CC + tx] = (__bf16)tile[tx][hwl];
        }
    } else {
        const int lb  = bid - (CVB + XPB);
        const int q   = lb & 3;
        const int t64 = lb >> 2;
        float* g = sm;
        for (int i = tid; i < 2048; i += 256)
            g[i] = gate_w[(size_t)(i >> 8) * CC + q * 256 + (i & 255)];
        __syncthreads();
        const int q2 = tid >> 6, tl = tid & 63;
        const int t  = t64 * 64 + tl;
        const int b  = t >> 12, hw = t & 4095;
        const float* xp = hs + (size_t)b * CC * HWH + hw;
        float l[EE];
#pragma unroll
        for (int e = 0; e < EE; ++e) l[e] = 0.0f;
        const int cbase = q * 256 + q2 * 64;
        for (int c2 = 0; c2 < 64; ++c2) {
            const float xv = xp[(size_t)(cbase + c2) * HWH];
#pragma unroll
            for (int e = 0; e < EE; ++e) l[e] += xv * g[e * 256 + q2 * 64 + c2];
        }
        float* dst = logP + ((size_t)(q * 4 + q2) * TT + t) * 8;
        f32x4 a, c;
#pragma unroll
        for (int e = 0; e < 4; ++e) { a[e] = l[e]; c[e] = l[4 + e]; }
        *(f32x4*)dst = a;
        *(f32x4*)&dst[4] = c;
    }
}

// ---------------------------------------------------------------------------
// k_top2 (unchanged R8)
// ---------------------------------------------------------------------------
__global__ __launch_bounds__(256) void k_top2(const float* __restrict__ logP,
                                              int* __restrict__ cnt,
                                              int* __restrict__ idxl,
                                              int* __restrict__ tokE,
                                              int* __restrict__ tokP,
                                              float* __restrict__ tokW) {
    __shared__ int lcnt[EE], lbase[EE];
    const int tid = threadIdx.x;
    const int t   = blockIdx.x * 256 + tid;
    if (tid < EE) lcnt[tid] = 0;
    __syncthreads();

    float l[EE];
#pragma unroll
    for (int e = 0; e < EE; ++e) l[e] = 0.0f;
#pragma unroll
    for (int pq = 0; pq < 16; ++pq) {
        const float* src = logP + ((size_t)pq * TT + t) * 8;
        const f32x4 a = *(const f32x4*)src;
        const f32x4 c = *(const f32x4*)&src[4];
#pragma unroll
        for (int e = 0; e < 4; ++e) { l[e] += a[e]; l[4 + e] += c[e]; }
    }

    int e1 = 0; float v1 = l[0];
#pragma unroll
    for (int e = 1; e < EE; ++e) { if (l[e] > v1) { v1 = l[e]; e1 = e; } }
    int e2 = -1; float v2 = -1e30f;
#pragma unroll
    for (int e = 0; e < EE; ++e) { if (e != e1 && l[e] > v2) { v2 = l[e]; e2 = e; } }

    const float p2 = __expf(v2 - v1);
    const float rs = 1.0f / (1.0f + p2);

    const int m1 = atomicAdd(&lcnt[e1], 1);
    const int m2 = atomicAdd(&lcnt[e2], 1);
    __syncthreads();
    if (tid < EE) lbase[tid] = atomicAdd(&cnt[tid], lcnt[tid]);
    __syncthreads();
    const int p1pos = lbase[e1] + m1;
    const int p2pos = lbase[e2] + m2;

    idxl[e1 * TT + p1pos] = t;
    idxl[e2 * TT + p2pos] = t;
    tokE[t] = e1 | (e2 << 8);
    tokP[2 * t]     = p1pos;
    tokP[2 * t + 1] = p2pos;
    tokW[2 * t]     = rs;
    tokW[2 * t + 1] = p2 * rs;
}

// ---------------------------------------------------------------------------
// Shared GEMM tile body (R8, proven): 3-slot ring, BK=32, counted vmcnt(3).
// ---------------------------------------------------------------------------
#define GT_TILE(SR, SS, KB, STG, WC) do {                                     \
    if (STG) {                                                                \
        gl_lds16(gA0 + (KB), &sA[SS][stA]);                                   \
        gl_lds16(gA1 + (KB), &sA[SS][stA + 4096]);                            \
        gl_lds16(gB0 + (KB), &sB[SS][stA]);                                   \
    }                                                                         \
    bf16x8 af[4], bv[4];                                                      \
    _Pragma("unroll") for (int f_ = 0; f_ < 4; ++f_) {                        \
        af[f_] = *(const bf16x8*)&sA[SR][aoff + f_ * 512];                    \
        bv[f_] = *(const bf16x8*)&sB[SR][boff + f_ * 512];                    \
    }                                                                         \
    PRIO1();                                                                  \
    _Pragma("unroll") for (int m_ = 0; m_ < 4; ++m_)                          \
    _Pragma("unroll") for (int n_ = 0; n_ < 4; ++n_)                          \
        acc[m_][n_] = __builtin_amdgcn_mfma_f32_16x16x32_bf16(                \
            af[m_], bv[n_], acc[m_][n_], 0, 0, 0);                            \
    PRIO0();                                                                  \
    WC;                                                                       \
    barrier_raw();                                                            \
} while (0)

// full K loop (prologue + 32 K-tiles), EXACTLY R8's verified schedule.
// Tiles 30/31 have STG=0 (tile 31 was staged at loop-iteration 9; staging
// anything at tile 30 would race its own slot-0 reads -- the R10 NaN bug).
#define GT_KLOOP() do {                                                       \
    gl_lds16(gA0,      &sA[0][stA]); gl_lds16(gA1,      &sA[0][stA + 4096]); \
    gl_lds16(gB0,      &sB[0][stA]);                                          \
    gl_lds16(gA0 + 32, &sA[1][stA]); gl_lds16(gA1 + 32, &sA[1][stA + 4096]); \
    gl_lds16(gB0 + 32, &sB[1][stA]);                                          \
    WAITV(3);                                                                 \
    barrier_raw();                                                            \
    int kb = 64;                                                              \
    for (int t3 = 0; t3 < 10; ++t3) {                                         \
        GT_TILE(0, 2, kb, 1, WAITV(3)); kb += 32;                             \
        GT_TILE(1, 0, kb, 1, WAITV(3)); kb += 32;                             \
        GT_TILE(2, 1, kb, 1, WAITV(3)); kb += 32;                             \
    }                                                                         \
    GT_TILE(0, 0, 0, 0, WAITV(0));                                            \
    GT_TILE(1, 0, 0, 0, (void)0);                                             \
} while (0)

// map tile index -> (expert, mtile, group offset); 8-iter predicated scan
#define TILE_MAP(TIX, E, MT, GOFF) do {                                       \
    int ty_ = (TIX); int ar_ = 0; E = 0; MT = 0; GOFF = 0;                    \
    _Pragma("unroll") for (int ee_ = 0; ee_ < EE; ++ee_) {                    \
        const int me_ = (cnt[ee_] + 255) >> 8;                                \
        if (ty_ >= 0 && ty_ < me_) { E = ee_; MT = ty_ << 8; GOFF = ar_; }    \
        ty_ -= me_; ar_ += me_ << 8;                                          \
    }                                                                         \
} while (0)

// ---------------------------------------------------------------------------
// k_gemm1 (R8 fallback): BM=256, BN=64 dual-W, 3-slot ring.
// ---------------------------------------------------------------------------
__global__ __launch_bounds__(512, 4)
void k_gemm1(const __bf16* __restrict__ X, const __bf16* __restrict__ w1b,
             const __bf16* __restrict__ w3b, const int* __restrict__ cnt,
             const int* __restrict__ idxl, __bf16* __restrict__ H) {
    const int lid = blockIdx.y * 16 + blockIdx.x;
    const int wg  = xcd_swz(lid, 16 * MAXTILES);
    const int n0  = (wg & 15) * 64;
    int e, mt, goff;
    TILE_MAP(wg >> 4, e, mt, goff);
    {
        int nT = 0;
#pragma unroll
        for (int ee = 0; ee < EE; ++ee) nT += (cnt[ee] + 255) >> 8;
        if ((wg >> 4) >= nT) return;
    }
    const int cntE = cnt[e];
    const __bf16* W1 = w1b + (size_t)e * FFN * CC;
    const __bf16* W3 = w3b + (size_t)e * FFN * CC;

    __shared__ __align__(16) __bf16 sA[3][8192];
    __shared__ __align__(16) __bf16 sB[3][4096];

    const int tid  = threadIdx.x;
    const int lane = tid & 63, wave = tid >> 6;
    const int l15  = lane & 15, lq = lane >> 4;
    const int wm   = wave & 3;
    const int wq   = wave >> 2;
    const int rsw  = (lq ^ ((l15 >> 1) & 3)) * 8;
    const int csw  = ((tid & 3) ^ ((tid >> 3) & 3)) * 8;
    const int cswb = ((lane & 3) ^ ((lane >> 3) & 3)) * 8;

    int pr0 = mt + (tid >> 2);        if (pr0 > cntE - 1) pr0 = cntE - 1;
    int pr1 = mt + 128 + (tid >> 2);  if (pr1 > cntE - 1) pr1 = cntE - 1;
    const __bf16* gA0 = X + (size_t)idxl[e * TT + pr0] * CC + csw;
    const __bf16* gA1 = X + (size_t)idxl[e * TT + pr1] * CC + csw;
    const __bf16* WB  = (wave & 1) ? W3 : W1;
    const __bf16* gB0 = WB + (size_t)(n0 + (wave >> 1) * 16 + (lane >> 2)) * CC + cswb;

    const int stA  = wave * 512;
    const int aoff = (wm * 64 + l15) * 32 + rsw;
    const int boff = (wq * 64 + l15) * 32 + rsw;

    f32x4 acc[4][4] = {};
    GT_KLOOP();

#pragma unroll
    for (int mf = 0; mf < 4; ++mf) {
        const int gr  = goff + mt + wm * 64 + mf * 16 + lq * 4;
        const int col = n0 + wq * 32 + l15;
#pragma unroll
        for (int r = 0; r < 4; ++r) {
            const float a0 = acc[mf][0][r], c0 = acc[mf][1][r];
            const float a1 = acc[mf][2][r], c1 = acc[mf][3][r];
            H[(size_t)(gr + r) * FFN + col]      = (__bf16)(gelu_fast(a0) * c0);
            H[(size_t)(gr + r) * FFN + col + 16] = (__bf16)(gelu_fast(a1) * c1);
        }
    }
}

// ---------------------------------------------------------------------------
// k_gemm2 (R8 fallback): BM=256, BN=128, 3-slot ring.
// ---------------------------------------------------------------------------
__global__ __launch_bounds__(512, 4)
void k_gemm2(const __bf16* __restrict__ H, const __bf16* __restrict__ w2b,
             const int* __restrict__ cnt, __bf16* __restrict__ Z) {
    const int lid = blockIdx.y * 8 + blockIdx.x;
    const int wg  = xcd_swz(lid, 8 * MAXTILES);
    const int n0  = (wg & 7) * 128;
    int e, mt, goff;
    TILE_MAP(wg >> 3, e, mt, goff);
    {
        int nT = 0;
#pragma unroll
        for (int ee = 0; ee < EE; ++ee) nT += (cnt[ee] + 255) >> 8;
        if ((wg >> 3) >= nT) return;
    }
    const __bf16* W2 = w2b + (size_t)e * CC * FFN;
    const __bf16* Ar = H + (size_t)(goff + mt) * FFN;

    __shared__ __align__(16) __bf16 sA[3][8192];
    __shared__ __align__(16) __bf16 sB[3][4096];

    const int tid  = threadIdx.x;
    const int lane = tid & 63, wave = tid >> 6;
    const int l15  = lane & 15, lq = lane >> 4;
    const int wm   = wave & 3;
    const int wq   = wave >> 2;
    const int rsw  = (lq ^ ((l15 >> 1) & 3)) * 8;
    const int csw  = ((tid & 3) ^ ((tid >> 3) & 3)) * 8;
    const int cswb = ((lane & 3) ^ ((lane >> 3) & 3)) * 8;

    const __bf16* gA0 = Ar + (size_t)(tid >> 2) * FFN + csw;
    const __bf16* gA1 = Ar + (size_t)(128 + (tid >> 2)) * FFN + csw;
    const __bf16* gB0 = W2 + (size_t)(n0 + wave * 16 + (lane >> 2)) * FFN + cswb;

    const int stA  = wave * 512;
    const int aoff = (wm * 64 + l15) * 32 + rsw;
    const int boff = (wq * 64 + l15) * 32 + rsw;

    f32x4 acc[4][4] = {};
    GT_KLOOP();

#pragma unroll
    for (int mf = 0; mf < 4; ++mf) {
        const int gr = goff + mt + wm * 64 + mf * 16 + lq * 4;
#pragma unroll
        for (int nf = 0; nf < 4; ++nf) {
            const int col = n0 + wq * 64 + nf * 16 + l15;
#pragma unroll
            for (int r = 0; r < 4; ++r)
                Z[(size_t)(gr + r) * CC + col] = (__bf16)acc[mf][nf][r];
        }
    }
}

// ---------------------------------------------------------------------------
// k_moe: FUSED persistent gemm1+gemm2.  512 blocks, all co-resident
// (2/CU: LDS 72 KiB, VGPR<=128).  Phase1 items base+512r (base =
// xcd_swz -> same-XCD tile grouping); phase2 items (511-base)+512r
// (reversed so phase-2 extras land on blocks without phase-1 extras).
// Per-tile readiness via agent-scope release/acquire on done1[tile]
// (relaxed polling, single acquire on success -> one cache-inv per item).
// Inner loops = R8 verbatim via GT_KLOOP.
// ---------------------------------------------------------------------------
__global__ __launch_bounds__(512, 4)
void k_moe(const __bf16* __restrict__ X, const __bf16* __restrict__ w1b,
           const __bf16* __restrict__ w3b, const __bf16* __restrict__ w2b,
           const int* __restrict__ cnt, const int* __restrict__ idxl,
           __bf16* __restrict__ H, __bf16* __restrict__ Z,
           int* __restrict__ done1) {
    __shared__ __align__(16) __bf16 sA[3][8192];
    __shared__ __align__(16) __bf16 sB[3][4096];

    const int tid  = threadIdx.x;
    const int lane = tid & 63, wave = tid >> 6;
    const int l15  = lane & 15, lq = lane >> 4;
    const int wm   = wave & 3;
    const int wq   = wave >> 2;
    const int rsw  = (lq ^ ((l15 >> 1) & 3)) * 8;
    const int csw  = ((tid & 3) ^ ((tid >> 3) & 3)) * 8;
    const int cswb = ((lane & 3) ^ ((lane >> 3) & 3)) * 8;
    const int stA  = wave * 512;
    const int aoff = (wm * 64 + l15) * 32 + rsw;
    const int boff = (wq * 64 + l15) * 32 + rsw;

    int nT = 0;
#pragma unroll
    for (int ee = 0; ee < EE; ++ee) nT += (cnt[ee] + 255) >> 8;
    const int n1 = nT * 16, n2 = nT * 8;
    const int base = xcd_swz(blockIdx.x, 512);

    // ---------------- phase 1: gemm1 items ----------------
    for (int it = base; it < n1; it += 512) {
        const int tix = it >> 4;
        const int n0  = (it & 15) * 64;
        int e, mt, goff;
        TILE_MAP(tix, e, mt, goff);
        const int cntE = cnt[e];
        const __bf16* W1 = w1b + (size_t)e * FFN * CC;
        const __bf16* W3 = w3b + (size_t)e * FFN * CC;

        int pr0 = mt + (tid >> 2);        if (pr0 > cntE - 1) pr0 = cntE - 1;
        int pr1 = mt + 128 + (tid >> 2);  if (pr1 > cntE - 1) pr1 = cntE - 1;
        const __bf16* gA0 = X + (size_t)idxl[e * TT + pr0] * CC + csw;
        const __bf16* gA1 = X + (size_t)idxl[e * TT + pr1] * CC + csw;
        const __bf16* WB  = (wave & 1) ? W3 : W1;
        const __bf16* gB0 = WB + (size_t)(n0 + (wave >> 1) * 16 + (lane >> 2)) * CC + cswb;

        f32x4 acc[4][4] = {};
        GT_KLOOP();

#pragma unroll
        for (int mf = 0; mf < 4; ++mf) {
            const int gr  = goff + mt + wm * 64 + mf * 16 + lq * 4;
            const int col = n0 + wq * 32 + l15;
#pragma unroll
            for (int r = 0; r < 4; ++r) {
                const float a0 = acc[mf][0][r], c0 = acc[mf][1][r];
                const float a1 = acc[mf][2][r], c1 = acc[mf][3][r];
                H[(size_t)(gr + r) * FFN + col]      = (__bf16)(gelu_fast(a0) * c0);
                H[(size_t)(gr + r) * FFN + col + 16] = (__bf16)(gelu_fast(a1) * c1);
            }
        }
        __threadfence();         // make this thread's H stores device-visible
        __syncthreads();         // all threads' fences complete
        if (tid == 0)
            __hip_atomic_fetch_add(&done1[tix], 1, __ATOMIC_RELEASE,
                                   __HIP_MEMORY_SCOPE_AGENT);
    }

    // ---------------- phase 2: gemm2 items (reversed base) ----------------
    for (int it = 511 - base; it < n2; it += 512) {
        const int tix = it >> 3;
        const int n0  = (it & 7) * 128;
        // wait until all 16 gemm1 n-items of this tile are done
        if (tid == 0) {
            int guard = 0;
            while (__hip_atomic_load(&done1[tix], __ATOMIC_RELAXED,
                                     __HIP_MEMORY_SCOPE_AGENT) < 16 &&
                   ++guard < (1 << 24))
                __builtin_amdgcn_s_sleep(8);
            // single acquire: orders + invalidates once on success
            (void)__hip_atomic_load(&done1[tix], __ATOMIC_ACQUIRE,
                                    __HIP_MEMORY_SCOPE_AGENT);
        }
        __syncthreads();

        int e, mt, goff;
        TILE_MAP(tix, e, mt, goff);
        const __bf16* W2 = w2b + (size_t)e * CC * FFN;
        const __bf16* Ar = H + (size_t)(goff + mt) * FFN;

        const __bf16* gA0 = Ar + (size_t)(tid >> 2) * FFN + csw;
        const __bf16* gA1 = Ar + (size_t)(128 + (tid >> 2)) * FFN + csw;
        const __bf16* gB0 = W2 + (size_t)(n0 + wave * 16 + (lane >> 2)) * FFN + cswb;

        f32x4 acc[4][4] = {};
        GT_KLOOP();

#pragma unroll
        for (int mf = 0; mf < 4; ++mf) {
            const int gr = goff + mt + wm * 64 + mf * 16 + lq * 4;
#pragma unroll
            for (int nf = 0; nf < 4; ++nf) {
                const int col = n0 + wq * 64 + nf * 16 + l15;
#pragma unroll
                for (int r = 0; r < 4; ++r)
                    Z[(size_t)(gr + r) * CC + col] = (__bf16)acc[mf][nf][r];
            }
        }
        __syncthreads();   // LDS ring reuse safety across items
    }
}

// ---------------------------------------------------------------------------
// k_combine (unchanged R8)
// ---------------------------------------------------------------------------
__global__ __launch_bounds__(256) void k_combine(const __bf16* __restrict__ Z,
                                                 const int* __restrict__ cnt,
                                                 const int* __restrict__ tokE,
                                                 const int* __restrict__ tokP,
                                                 const float* __restrict__ tokW,
                                                 float* __restrict__ out) {
    __shared__ float tile[32][33];
    __shared__ int s_pre[EE];
    const int tid = threadIdx.x;
    if (tid < EE) {
        int a = 0;
        for (int ee = 0; ee < tid; ++ee) a += ((cnt[ee] + 255) >> 8) << 8;
        s_pre[tid] = a;
    }
    __syncthreads();

    const int t0 = blockIdx.x * 32;
    const int c0 = blockIdx.y * 32;
    const int tx = tid & 31;
    const int ty = tid >> 5;

#pragma unroll
    for (int i = 0; i < 4; ++i) {
        const int tl = ty + 8 * i;
        const int t  = t0 + tl;
        const int ee = tokE[t];
        const int e1 = ee & 0xff, e2 = ee >> 8;
        const int r1 = s_pre[e1] + tokP[2 * t];
        const int r2 = s_pre[e2] + tokP[2 * t + 1];
        const float v = tokW[2 * t]     * (float)Z[(size_t)r1 * CC + c0 + tx]
                      + tokW[2 * t + 1] * (float)Z[(size_t)r2 * CC + c0 + tx];
        tile[tl][tx] = v;
    }
    __syncthreads();

    const int b   = t0 >> 12;
    const int hw0 = t0 & 4095;
#pragma unroll
    for (int i = 0; i < 4; ++i) {
        const int cl = ty + 8 * i;
        out[(size_t)b * CC * HWH + (size_t)(c0 + cl) * HWH + hw0 + tx] = tile[tx][cl];
    }
}

// ---------------------------------------------------------------------------
extern "C" void kernel_launch(void* const* d_in, const int* in_sizes, int n_in,
                              void* d_out, int out_size, void* d_ws, size_t ws_size,
                              hipStream_t stream) {
    const float* hs     = (const float*)d_in[0];
    const float* gate_w = (const float*)d_in[1];
    const float* w1     = (const float*)d_in[2];
    const float* w2     = (const float*)d_in[3];
    const float* w3     = (const float*)d_in[4];
    float* out = (float*)d_out;

    const size_t WSZ = (size_t)EE * FFN * CC * 2;   // 16 MB per bf16 weight
    const size_t HFB = (size_t)HCAP * FFN * 2;      // 37,224,448
    char* ws = (char*)d_ws;
    __bf16* w2b  = (__bf16*)ws;                     // [0, 16M)
    __bf16* w1b  = (__bf16*)(ws + WSZ);             // [16M,32M)
    __bf16* w3b  = (__bf16*)(ws + 2 * WSZ);         // [32M,48M)
    __bf16* X    = (__bf16*)(ws + 3 * WSZ);         // [48M,64M)
    __bf16* Hbuf = (__bf16*)(ws + 4 * WSZ);
    float*  logP = (float*)Hbuf;                    // dead before gemm1
    char* p = ws + 4 * WSZ + HFB;
    int*   idxl  = (int*)p;           p += (size_t)EE * TT * 4;
    int*   tokE  = (int*)p;           p += (size_t)TT * 4;
    int*   tokP  = (int*)p;           p += (size_t)2 * TT * 4;
    float* tokW  = (float*)p;         p += (size_t)2 * TT * 4;
    int*   cnt   = (int*)p;           p += 1024;    // 256 ints
    int*   done1 = (int*)p;           p += 2048;    // 512 ints
    const size_t off_end = (size_t)(p - ws);
    const size_t need_fused = off_end + (size_t)HCAP * CC * 2;

    const bool fused = (ws_size >= need_fused);
    // Z location: fused -> fresh region after everything; fallback -> R8
    // overlay of w1b/w3b/X-head (dead after gemm1 in the sequential path).
    __bf16* Zf   = (__bf16*)(ws + off_end);
    __bf16* Zovl = (__bf16*)(ws + WSZ);

    // zero cnt + done1 in one memset
    hipMemsetAsync(cnt, 0, 1024 + 2048, stream);

    k_prep<<<CVB + XPB + RTB, 256, 0, stream>>>(
        hs, gate_w, w1, w2, w3, w1b, w2b, w3b, X, logP);
    k_top2<<<TT / 256, 256, 0, stream>>>(logP, cnt, idxl, tokE, tokP, tokW);

    if (fused) {
        k_moe<<<512, 512, 0, stream>>>(X, w1b, w3b, w2b, cnt, idxl,
                                       Hbuf, Zf, done1);
        k_combine<<<dim3(TT / 32, CC / 32), 256, 0, stream>>>(
            Zf, cnt, tokE, tokP, tokW, out);
    } else {
        k_gemm1<<<dim3(FFN / 64, MAXTILES), 512, 0, stream>>>(
            X, w1b, w3b, cnt, idxl, Hbuf);
        k_gemm2<<<dim3(CC / 128, MAXTILES), 512, 0, stream>>>(
            Hbuf, w2b, cnt, Zovl);
        k_combine<<<dim3(TT / 32, CC / 32), 256, 0, stream>>>(
            Zovl, cnt, tokE, tokP, tokW, out);
    }
}

// Round 12
// 322.157 us; speedup vs baseline: 4.3431x; 2.5123x over previous
//
#include <hip/hip_runtime.h>
#include <hip/hip_bf16.h>
#include <math.h>

// Problem constants
#define BB 2
#define CC 1024
#define HH 64
#define WW 64
#define HWH (HH*WW)          // 4096
#define TT (BB*HWH)          // 8192 tokens
#define EE 8
#define FFN 1024
// group padding stays 256-granular (H/Z layout); m-tiles are 128-granular
#define MAXTILES 71          // sum_e ceil(cnt_e/256) <= 64+7
#define MAXT128 135          // sum_e ceil(cnt_e/128) <= 128+7
#define HCAP (MAXTILES*256)  // 18176 padded rows

typedef __bf16 bf16x8 __attribute__((ext_vector_type(8)));
typedef float  f32x4  __attribute__((ext_vector_type(4)));

// async global->LDS, 16B per lane. LDS dest = wave-uniform base + lane*16.
__device__ __forceinline__ void gl_lds16(const __bf16* g, __bf16* l) {
    __builtin_amdgcn_global_load_lds(
        (const __attribute__((address_space(1))) void*)g,
        (__attribute__((address_space(3))) void*)l, 16, 0, 0);
}

__device__ __forceinline__ void barrier_raw() {
    asm volatile("" ::: "memory");
    __builtin_amdgcn_s_barrier();
    asm volatile("" ::: "memory");
}

// bijective XCD chunk swizzle (m204): consecutive work-ids -> same XCD chunk.
__device__ __forceinline__ int xcd_swz(int orig, int nwg) {
    const int q = nwg >> 3, r = nwg & 7, x = orig & 7, o8 = orig >> 3;
    return (x < r ? x * (q + 1) : r * (q + 1) + (x - r) * q) + o8;
}

// fast exact-enough GELU (tanh form): max |diff vs erf-GELU| ~7e-4.
__device__ __forceinline__ float gelu_fast(float a) {
    const float a2 = a * a;
    const float t  = a * fmaf(0.044715f, a2, 1.0f);
    const float u  = __builtin_amdgcn_exp2f(t * -2.30220795f);
    return a * __builtin_amdgcn_rcpf(1.0f + u);
}

#define WAITV(N) asm volatile("s_waitcnt vmcnt(" #N ")" ::: "memory")
#define PRIO1()  __builtin_amdgcn_s_setprio(1)
#define PRIO0()  __builtin_amdgcn_s_setprio(0)

// ---------------------------------------------------------------------------
// k_prep (unchanged R8)
// ---------------------------------------------------------------------------
#define CVB 12288
#define XPB 8192
#define RTB 512
__global__ __launch_bounds__(256) void k_prep(
    const float* __restrict__ hs, const float* __restrict__ gate_w,
    const float* __restrict__ w1, const float* __restrict__ w2,
    const float* __restrict__ w3,
    __bf16* __restrict__ w1b, __bf16* __restrict__ w2b,
    __bf16* __restrict__ w3b, __bf16* __restrict__ X,
    float* __restrict__ logP) {
    __shared__ float sm[2112];
    const int bid = blockIdx.x;
    const int tid = threadIdx.x;

    if (bid < CVB) {
        const float* s; __bf16* d; int lb = bid;
        if (lb < 4096)      { s = w1; d = w1b; }
        else if (lb < 8192) { s = w2; d = w2b; lb -= 4096; }
        else                { s = w3; d = w3b; lb -= 8192; }
        const size_t i = (size_t)lb * 2048 + (size_t)tid * 8;
        const f32x4 v0 = *(const f32x4*)&s[i];
        const f32x4 v1 = *(const f32x4*)&s[i + 4];
        bf16x8 o;
#pragma unroll
        for (int j = 0; j < 4; ++j) { o[j] = (__bf16)v0[j]; o[4 + j] = (__bf16)v1[j]; }
        *(bf16x8*)&d[i] = o;
    } else if (bid < CVB + XPB) {
        const int lb  = bid - CVB;
        const int hw0 = (lb & 127) * 32;
        const int c0  = ((lb >> 7) & 31) * 32;
        const int b   = lb >> 12;
        float (*tile)[33] = (float(*)[33])sm;
        const int tx = tid & 31, ty = tid >> 5;
        const float* src = hs + ((size_t)b * CC + c0) * HWH + hw0;
#pragma unroll
        for (int i = 0; i < 4; ++i)
            tile[ty + i * 8][tx] = src[(size_t)(ty + i * 8) * HWH + tx];
        __syncthreads();
        __bf16* dst = X + ((size_t)b * HWH + hw0) * CC + c0;
#pragma unroll
        for (int i = 0; i < 4; ++i) {
            const int hwl = ty + i * 8;
            dst[(size_t)hwl * CC + tx] = (__bf16)tile[tx][hwl];
        }
    } else {
        const int lb  = bid - (CVB + XPB);
        const int q   = lb & 3;
        const int t64 = lb >> 2;
        float* g = sm;
        for (int i = tid; i < 2048; i += 256)
            g[i] = gate_w[(size_t)(i >> 8) * CC + q * 256 + (i & 255)];
        __syncthreads();
        const int q2 = tid >> 6, tl = tid & 63;
        const int t  = t64 * 64 + tl;
        const int b  = t >> 12, hw = t & 4095;
        const float* xp = hs + (size_t)b * CC * HWH + hw;
        float l[EE];
#pragma unroll
        for (int e = 0; e < EE; ++e) l[e] = 0.0f;
        const int cbase = q * 256 + q2 * 64;
        for (int c2 = 0; c2 < 64; ++c2) {
            const float xv = xp[(size_t)(cbase + c2) * HWH];
#pragma unroll
            for (int e = 0; e < EE; ++e) l[e] += xv * g[e * 256 + q2 * 64 + c2];
        }
        float* dst = logP + ((size_t)(q * 4 + q2) * TT + t) * 8;
        f32x4 a, c;
#pragma unroll
        for (int e = 0; e < 4; ++e) { a[e] = l[e]; c[e] = l[4 + e]; }
        *(f32x4*)dst = a;
        *(f32x4*)&dst[4] = c;
    }
}

// ---------------------------------------------------------------------------
// k_top2 (unchanged R8)
// ---------------------------------------------------------------------------
__global__ __launch_bounds__(256) void k_top2(const float* __restrict__ logP,
                                              int* __restrict__ cnt,
                                              int* __restrict__ idxl,
                                              int* __restrict__ tokE,
                                              int* __restrict__ tokP,
                                              float* __restrict__ tokW) {
    __shared__ int lcnt[EE], lbase[EE];
    const int tid = threadIdx.x;
    const int t   = blockIdx.x * 256 + tid;
    if (tid < EE) lcnt[tid] = 0;
    __syncthreads();

    float l[EE];
#pragma unroll
    for (int e = 0; e < EE; ++e) l[e] = 0.0f;
#pragma unroll
    for (int pq = 0; pq < 16; ++pq) {
        const float* src = logP + ((size_t)pq * TT + t) * 8;
        const f32x4 a = *(const f32x4*)src;
        const f32x4 c = *(const f32x4*)&src[4];
#pragma unroll
        for (int e = 0; e < 4; ++e) { l[e] += a[e]; l[4 + e] += c[e]; }
    }

    int e1 = 0; float v1 = l[0];
#pragma unroll
    for (int e = 1; e < EE; ++e) { if (l[e] > v1) { v1 = l[e]; e1 = e; } }
    int e2 = -1; float v2 = -1e30f;
#pragma unroll
    for (int e = 0; e < EE; ++e) { if (e != e1 && l[e] > v2) { v2 = l[e]; e2 = e; } }

    const float p2 = __expf(v2 - v1);
    const float rs = 1.0f / (1.0f + p2);

    const int m1 = atomicAdd(&lcnt[e1], 1);
    const int m2 = atomicAdd(&lcnt[e2], 1);
    __syncthreads();
    if (tid < EE) lbase[tid] = atomicAdd(&cnt[tid], lcnt[tid]);
    __syncthreads();
    const int p1pos = lbase[e1] + m1;
    const int p2pos = lbase[e2] + m2;

    idxl[e1 * TT + p1pos] = t;
    idxl[e2 * TT + p2pos] = t;
    tokE[t] = e1 | (e2 << 8);
    tokP[2 * t]     = p1pos;
    tokP[2 * t + 1] = p2pos;
    tokW[2 * t]     = rs;
    tokW[2 * t + 1] = p2 * rs;
}

// ---------------------------------------------------------------------------
// 4-wave GEMM tile body: 3-slot ring, BK=32, 4 loads/tile (A x2, B x2),
// counted WAITV(4) (R8's proven schedule shape, halved block).
// Ledger: tile t start -> outstanding = t+1's 4; issue t+2's 4 -> 8;
// WAITV(4) drains t+1's -> ready for next tile.  1 barrier/tile.
// ---------------------------------------------------------------------------
#define GT4_TILE(SR, SS, KB, STG, WC) do {                                    \
    if (STG) {                                                                \
        gl_lds16(gA0 + (KB), &sA[SS][stA]);                                   \
        gl_lds16(gA1 + (KB), &sA[SS][stA + 2048]);                            \
        gl_lds16(gB0 + (KB), &sB[SS][stA]);                                   \
        gl_lds16(gB1 + (KB), &sB[SS][stA + 2048]);                            \
    }                                                                         \
    bf16x8 af[4], bv[4];                                                      \
    _Pragma("unroll") for (int f_ = 0; f_ < 4; ++f_) {                        \
        af[f_] = *(const bf16x8*)&sA[SR][aoff + f_ * 512];                    \
        bv[f_] = *(const bf16x8*)&sB[SR][boff + f_ * 512];                    \
    }                                                                         \
    PRIO1();                                                                  \
    _Pragma("unroll") for (int m_ = 0; m_ < 4; ++m_)                          \
    _Pragma("unroll") for (int n_ = 0; n_ < 4; ++n_)                          \
        acc[m_][n_] = __builtin_amdgcn_mfma_f32_16x16x32_bf16(                \
            af[m_], bv[n_], acc[m_][n_], 0, 0, 0);                            \
    PRIO0();                                                                  \
    WC;                                                                       \
    barrier_raw();                                                            \
} while (0)

// prologue + 32 K-tiles; tiles 30/31 STG=0 (31 staged at loop iter 9)
#define GT4_KLOOP() do {                                                      \
    gl_lds16(gA0,      &sA[0][stA]); gl_lds16(gA1,      &sA[0][stA + 2048]); \
    gl_lds16(gB0,      &sB[0][stA]); gl_lds16(gB1,      &sB[0][stA + 2048]); \
    gl_lds16(gA0 + 32, &sA[1][stA]); gl_lds16(gA1 + 32, &sA[1][stA + 2048]); \
    gl_lds16(gB0 + 32, &sB[1][stA]); gl_lds16(gB1 + 32, &sB[1][stA + 2048]); \
    WAITV(4);                                                                 \
    barrier_raw();                                                            \
    int kb = 64;                                                              \
    for (int t3 = 0; t3 < 10; ++t3) {                                         \
        GT4_TILE(0, 2, kb, 1, WAITV(4)); kb += 32;                            \
        GT4_TILE(1, 0, kb, 1, WAITV(4)); kb += 32;                            \
        GT4_TILE(2, 1, kb, 1, WAITV(4)); kb += 32;                            \
    }                                                                         \
    GT4_TILE(0, 0, 0, 0, WAITV(0));                                           \
    GT4_TILE(1, 0, 0, 0, (void)0);                                            \
} while (0)

// tile index (128-granular) -> (expert, mtile, 256-padded group offset)
#define TILE_MAP128(TIX, E, MT, GOFF) do {                                    \
    int ty_ = (TIX); int ar_ = 0; E = 0; MT = 0; GOFF = 0;                    \
    _Pragma("unroll") for (int ee_ = 0; ee_ < EE; ++ee_) {                    \
        const int me_ = (cnt[ee_] + 127) >> 7;                                \
        if (ty_ >= 0 && ty_ < me_) { E = ee_; MT = ty_ << 7; GOFF = ar_; }    \
        ty_ -= me_; ar_ += ((cnt[ee_] + 255) >> 8) << 8;                      \
    }                                                                         \
} while (0)

// ---------------------------------------------------------------------------
// GEMM1: H = gelu(X@W1^T)*(X@W3^T), bf16, grouped.
// BM=128, BN=64 (dual weights), BK=32.  256 thr / 4 waves (2m x 2n),
// per-wave 64x64 acc[4][4] (R8's proven per-wave schedule).  LDS 48 KiB
// (3-slot ring) -> 3 blocks/CU (768 slots; ~2112 items -> 3 rounds of t/2).
// grid (FFN/64, MAXT128), XCD-swizzled.
// ---------------------------------------------------------------------------
__global__ __launch_bounds__(256, 3)
void k_gemm1(const __bf16* __restrict__ X, const __bf16* __restrict__ w1b,
             const __bf16* __restrict__ w3b, const int* __restrict__ cnt,
             const int* __restrict__ idxl, __bf16* __restrict__ H) {
    const int lid = blockIdx.y * 16 + blockIdx.x;
    const int wg  = xcd_swz(lid, 16 * MAXT128);
    const int n0  = (wg & 15) * 64;          // H-column base
    const int tix = wg >> 4;
    {
        int nT = 0;
#pragma unroll
        for (int ee = 0; ee < EE; ++ee) nT += (cnt[ee] + 127) >> 7;
        if (tix >= nT) return;
    }
    int e, mt, goff;
    TILE_MAP128(tix, e, mt, goff);
    const int cntE = cnt[e];
    const __bf16* W1 = w1b + (size_t)e * FFN * CC;
    const __bf16* W3 = w3b + (size_t)e * FFN * CC;

    __shared__ __align__(16) __bf16 sA[3][4096];   // 24 KiB: 128 rows x 32
    __shared__ __align__(16) __bf16 sB[3][4096];   // 24 KiB: 128 rows x 32

    const int tid  = threadIdx.x;
    const int lane = tid & 63, wave = tid >> 6;
    const int l15  = lane & 15, lq = lane >> 4;
    const int wm   = wave & 1;     // 2 m-halves (64 rows each)
    const int wq   = wave >> 1;    // 2 n-halves (32 H-cols each)
    const int rsw  = (lq ^ ((l15 >> 1) & 3)) * 8;        // frag-read swizzle
    const int csw  = ((tid & 3) ^ ((tid >> 3) & 3)) * 8; // staging swizzle

    // A: gathered token rows mt + {0,64} + tid>>2 (clamped)
    const int r6 = tid >> 2;                 // 0..63
    int pr0 = mt + r6;       if (pr0 > cntE - 1) pr0 = cntE - 1;
    int pr1 = mt + 64 + r6;  if (pr1 > cntE - 1) pr1 = cntE - 1;
    const __bf16* gA0 = X + (size_t)idxl[e * TT + pr0] * CC + csw;
    const __bf16* gA1 = X + (size_t)idxl[e * TT + pr1] * CC + csw;
    // B-LDS rows (16-row groups): W1 c0-15 | W3 c0-15 | W1 c16-31 | W3 c16-31 |
    // W1 c32-47 | W3 c32-47 | W1 c48-63 | W3 c48-63.  Call 1 covers rows 0-63,
    // call 2 rows 64-127 (= same mat pattern, cols +32).
    const __bf16* WB  = (r6 & 16) ? W3 : W1;
    const __bf16* gB0 = WB + (size_t)(n0 + (r6 >> 5) * 16 + (r6 & 15)) * CC + csw;
    const __bf16* gB1 = gB0 + (size_t)32 * CC;

    const int stA  = wave * 512;                  // stage LDS elem base
    const int aoff = (wm * 64 + l15) * 32 + rsw;  // + mf*512
    const int boff = (wq * 64 + l15) * 32 + rsw;  // + nf*512

    f32x4 acc[4][4] = {};
    GT4_KLOOP();

    // epilogue: nf0=W1 / nf1=W3 @ col, nf2=W1 / nf3=W3 @ col+16
#pragma unroll
    for (int mf = 0; mf < 4; ++mf) {
        const int gr  = goff + mt + wm * 64 + mf * 16 + lq * 4;
        const int col = n0 + wq * 32 + l15;
#pragma unroll
        for (int r = 0; r < 4; ++r) {
            const float a0 = acc[mf][0][r], c0 = acc[mf][1][r];
            const float a1 = acc[mf][2][r], c1 = acc[mf][3][r];
            H[(size_t)(gr + r) * FFN + col]      = (__bf16)(gelu_fast(a0) * c0);
            H[(size_t)(gr + r) * FFN + col + 16] = (__bf16)(gelu_fast(a1) * c1);
        }
    }
}

// ---------------------------------------------------------------------------
// GEMM2: Z = H @ W2^T, bf16, grouped.  BM=128, BN=128, BK=32, 256 thr /
// 4 waves (2m x 2n), per-wave 64x64.  LDS 48 KiB -> 3 blocks/CU.
// grid (CC/128, MAXT128), XCD-swizzled.
// ---------------------------------------------------------------------------
__global__ __launch_bounds__(256, 3)
void k_gemm2(const __bf16* __restrict__ H, const __bf16* __restrict__ w2b,
             const int* __restrict__ cnt, __bf16* __restrict__ Z) {
    const int lid = blockIdx.y * 8 + blockIdx.x;
    const int wg  = xcd_swz(lid, 8 * MAXT128);
    const int n0  = (wg & 7) * 128;
    const int tix = wg >> 3;
    {
        int nT = 0;
#pragma unroll
        for (int ee = 0; ee < EE; ++ee) nT += (cnt[ee] + 127) >> 7;
        if (tix >= nT) return;
    }
    int e, mt, goff;
    TILE_MAP128(tix, e, mt, goff);
    const __bf16* W2 = w2b + (size_t)e * CC * FFN;
    const __bf16* Ar = H + (size_t)(goff + mt) * FFN;

    __shared__ __align__(16) __bf16 sA[3][4096];   // 24 KiB
    __shared__ __align__(16) __bf16 sB[3][4096];   // 24 KiB

    const int tid  = threadIdx.x;
    const int lane = tid & 63, wave = tid >> 6;
    const int l15  = lane & 15, lq = lane >> 4;
    const int wm   = wave & 1;
    const int wq   = wave >> 1;
    const int rsw  = (lq ^ ((l15 >> 1) & 3)) * 8;
    const int csw  = ((tid & 3) ^ ((tid >> 3) & 3)) * 8;

    const int r6 = tid >> 2;
    const __bf16* gA0 = Ar + (size_t)r6 * FFN + csw;
    const __bf16* gA1 = gA0 + (size_t)64 * FFN;
    const __bf16* gB0 = W2 + (size_t)(n0 + r6) * FFN + csw;
    const __bf16* gB1 = gB0 + (size_t)64 * FFN;

    const int stA  = wave * 512;
    const int aoff = (wm * 64 + l15) * 32 + rsw;
    const int boff = (wq * 64 + l15) * 32 + rsw;

    f32x4 acc[4][4] = {};
    GT4_KLOOP();

#pragma unroll
    for (int mf = 0; mf < 4; ++mf) {
        const int gr = goff + mt + wm * 64 + mf * 16 + lq * 4;
#pragma unroll
        for (int nf = 0; nf < 4; ++nf) {
            const int col = n0 + wq * 64 + nf * 16 + l15;
#pragma unroll
            for (int r = 0; r < 4; ++r)
                Z[(size_t)(gr + r) * CC + col] = (__bf16)acc[mf][nf][r];
        }
    }
}

// ---------------------------------------------------------------------------
// k_combine (unchanged R8)
// ---------------------------------------------------------------------------
__global__ __launch_bounds__(256) void k_combine(const __bf16* __restrict__ Z,
                                                 const int* __restrict__ cnt,
                                                 const int* __restrict__ tokE,
                                                 const int* __restrict__ tokP,
                                                 const float* __restrict__ tokW,
                                                 float* __restrict__ out) {
    __shared__ float tile[32][33];
    __shared__ int s_pre[EE];
    const int tid = threadIdx.x;
    if (tid < EE) {
        int a = 0;
        for (int ee = 0; ee < tid; ++ee) a += ((cnt[ee] + 255) >> 8) << 8;
        s_pre[tid] = a;
    }
    __syncthreads();

    const int t0 = blockIdx.x * 32;
    const int c0 = blockIdx.y * 32;
    const int tx = tid & 31;
    const int ty = tid >> 5;

#pragma unroll
    for (int i = 0; i < 4; ++i) {
        const int tl = ty + 8 * i;
        const int t  = t0 + tl;
        const int ee = tokE[t];
        const int e1 = ee & 0xff, e2 = ee >> 8;
        const int r1 = s_pre[e1] + tokP[2 * t];
        const int r2 = s_pre[e2] + tokP[2 * t + 1];
        const float v = tokW[2 * t]     * (float)Z[(size_t)r1 * CC + c0 + tx]
                      + tokW[2 * t + 1] * (float)Z[(size_t)r2 * CC + c0 + tx];
        tile[tl][tx] = v;
    }
    __syncthreads();

    const int b   = t0 >> 12;
    const int hw0 = t0 & 4095;
#pragma unroll
    for (int i = 0; i < 4; ++i) {
        const int cl = ty + 8 * i;
        out[(size_t)b * CC * HWH + (size_t)(c0 + cl) * HWH + hw0 + tx] = tile[tx][cl];
    }
}

// ---------------------------------------------------------------------------
extern "C" void kernel_launch(void* const* d_in, const int* in_sizes, int n_in,
                              void* d_out, int out_size, void* d_ws, size_t ws_size,
                              hipStream_t stream) {
    const float* hs     = (const float*)d_in[0];
    const float* gate_w = (const float*)d_in[1];
    const float* w1     = (const float*)d_in[2];
    const float* w2     = (const float*)d_in[3];
    const float* w3     = (const float*)d_in[4];
    float* out = (float*)d_out;

    const size_t WSZ = (size_t)EE * FFN * CC * 2;   // 16 MB per bf16 weight
    char* ws = (char*)d_ws;
    __bf16* w2b  = (__bf16*)ws;                     // [0, 16M)   live: gemm2
    __bf16* w1b  = (__bf16*)(ws + WSZ);             // [16M,32M)  live: gemm1
    __bf16* w3b  = (__bf16*)(ws + 2 * WSZ);         // [32M,48M)  live: gemm1
    __bf16* X    = (__bf16*)(ws + 3 * WSZ);         // [48M,64M)  live: gemm1
    __bf16* Zbuf = (__bf16*)(ws + WSZ);             // overlays w1b,w3b,X-head
    __bf16* Hbuf = (__bf16*)(ws + 4 * WSZ);         // ~35.5 MiB
    float*  logP = (float*)Hbuf;                    // 4 MB, dead before gemm1
    char* p = ws + 4 * WSZ + (size_t)HCAP * FFN * 2;
    int*   idxl  = (int*)p;           p += (size_t)EE * TT * 4;
    int*   tokE  = (int*)p;           p += (size_t)TT * 4;
    int*   tokP  = (int*)p;           p += (size_t)2 * TT * 4;
    float* tokW  = (float*)p;         p += (size_t)2 * TT * 4;
    int*   cnt   = (int*)p;           p += 256;

    hipMemsetAsync(cnt, 0, EE * sizeof(int), stream);

    k_prep<<<CVB + XPB + RTB, 256, 0, stream>>>(
        hs, gate_w, w1, w2, w3, w1b, w2b, w3b, X, logP);
    k_top2<<<TT / 256, 256, 0, stream>>>(logP, cnt, idxl, tokE, tokP, tokW);

    k_gemm1<<<dim3(FFN / 64, MAXT128), 256, 0, stream>>>(
        X, w1b, w3b, cnt, idxl, Hbuf);
    k_gemm2<<<dim3(CC / 128, MAXT128), 256, 0, stream>>>(
        Hbuf, w2b, cnt, Zbuf);
    k_combine<<<dim3(TT / 32, CC / 32), 256, 0, stream>>>(
        Zbuf, cnt, tokE, tokP, tokW, out);
}